// Round 1
// 334.895 us; speedup vs baseline: 1.0166x; 1.0166x over previous
//
#include <hip/hip_runtime.h>
#include <cstdint>
#include <math.h>

typedef __bf16 bf16_t;
typedef __bf16 bf16x8 __attribute__((ext_vector_type(8)));
typedef __bf16 bf16x4 __attribute__((ext_vector_type(4)));
typedef float f32x4 __attribute__((ext_vector_type(4)));

#define MFMA16(a, b, c) __builtin_amdgcn_mfma_f32_16x16x32_bf16((a), (b), (c), 0, 0, 0)

static constexpr int BATCH = 4;
static constexpr int SEQ = 2048;
static constexpr int DIMC = 1024;
static constexpr int NH = 16;
static constexpr int HD = 64;

__device__ __forceinline__ void async_copy16(void* lds, const void* g) {
    __builtin_amdgcn_global_load_lds(
        (const __attribute__((address_space(1))) void*)g,
        (__attribute__((address_space(3))) void*)lds, 16, 0, 0);
}

__device__ __forceinline__ float fast_exp2(float x) {
#if __has_builtin(__builtin_amdgcn_exp2f)
    return __builtin_amdgcn_exp2f(x);
#else
    return __expf(x * 0.6931471805599453f);
#endif
}

// ---------------- fp32 -> bf16 elementwise convert, 3 tensors -----------------
__global__ __launch_bounds__(256) void cvt3(const float* __restrict__ q,
                                            const float* __restrict__ k,
                                            const float* __restrict__ v,
                                            bf16_t* __restrict__ out) {
    const float* in = (blockIdx.y == 0) ? q : ((blockIdx.y == 1) ? k : v);
    bf16_t* o = out + (size_t)blockIdx.y * BATCH * SEQ * DIMC;
    const int i = blockIdx.x * 256 + threadIdx.x;  // 8 elems per thread
    const float4 f0 = ((const float4*)in)[i * 2];
    const float4 f1 = ((const float4*)in)[i * 2 + 1];
    bf16x8 vv;
    vv[0] = (bf16_t)f0.x; vv[1] = (bf16_t)f0.y; vv[2] = (bf16_t)f0.z; vv[3] = (bf16_t)f0.w;
    vv[4] = (bf16_t)f1.x; vv[5] = (bf16_t)f1.y; vv[6] = (bf16_t)f1.z; vv[7] = (bf16_t)f1.w;
    ((bf16x8*)o)[i] = vv;
}

// ---------------- weight transpose + fp32->bf16 convert -----------------
__global__ __launch_bounds__(256) void transpose_cvt(const float* __restrict__ W0,
                                                     const float* __restrict__ W1,
                                                     const float* __restrict__ W2,
                                                     const float* __restrict__ W3,
                                                     bf16_t* __restrict__ out) {
    const float* Ws[4] = {W0, W1, W2, W3};
    const float* W = Ws[blockIdx.z];
    bf16_t* Wt = out + (size_t)blockIdx.z * DIMC * DIMC;
    __shared__ float tile[32][33];
    const int tx = threadIdx.x & 31;
    const int ty = threadIdx.x >> 5;
    const int x0 = blockIdx.x * 32;
    const int y0 = blockIdx.y * 32;
    #pragma unroll
    for (int j = ty; j < 32; j += 8)
        tile[j][tx] = W[(size_t)(y0 + j) * DIMC + x0 + tx];
    __syncthreads();
    #pragma unroll
    for (int j = ty; j < 32; j += 8)
        Wt[(size_t)(x0 + j) * DIMC + y0 + tx] = (bf16_t)tile[tx][j];
}

// ---------------- rope tables -----------------
__global__ __launch_bounds__(256) void rope_tab(float* __restrict__ cosT, float* __restrict__ sinT) {
    const int idx = blockIdx.x * 256 + threadIdx.x;  // 65536 = 2048*32
    const int t = idx >> 5;
    const int p = idx & 31;
    const float inv = exp2f(-0.41524101186092029f * (float)p);
    const float ang = (float)t * inv;
    float s, c;
    sincosf(ang, &s, &c);
    cosT[idx] = c;
    sinT[idx] = s;
}

// ===== shared GEMM k-loop body (128x128 tile, BK=32, swizzled LDS) =====
// As/Bs layout: element (row r in [0,128), k-granule g in [0,4)) at
//   r*32 + ((g ^ f(r)) << 3), f(r) = (r&3)^((r>>2)&3).  <=2-way bank aliasing.
#define GEMM_KLOOP(A_, Bt_)                                                             \
    f32x4 acc[4][4] = {};                                                               \
    const int swW = ((lane >> 2) & 3) ^ ((lane >> 4) & 3); /* write-side f(r) */        \
    const int rIn = lane >> 2;                             /* row within chunk */       \
    const int gW = ((lane & 3) ^ swW) * 8;                 /* logical k offset */       \
    const int fR = (l15 & 3) ^ ((l15 >> 2) & 3);           /* read-side f(r) */         \
    for (int kt = 0; kt < DIMC / 32; ++kt) {                                            \
        const int k0 = kt * 32;                                                         \
        __syncthreads();                                                                \
        _Pragma("unroll") for (int ci = 0; ci < 2; ++ci) {                              \
            const int c = 2 * w + ci;                                                   \
            async_copy16(&Bs[c * 512], Bt_ + (size_t)(col0 + c * 16 + rIn) * DIMC + k0 + gW); \
            async_copy16(&As[c * 512], A_ + (size_t)(row0 + c * 16 + rIn) * DIMC + k0 + gW);  \
        }                                                                               \
        __syncthreads();                                                                \
        bf16x8 af[4], bfr[4];                                                           \
        _Pragma("unroll") for (int mt = 0; mt < 4; ++mt)                                \
            af[mt] = *(const bf16x8*)&As[(wr * 64 + mt * 16 + l15) * 32 + ((quad ^ fR) << 3)]; \
        _Pragma("unroll") for (int nt = 0; nt < 4; ++nt)                                \
            bfr[nt] = *(const bf16x8*)&Bs[(wc * 64 + nt * 16 + l15) * 32 + ((quad ^ fR) << 3)]; \
        _Pragma("unroll") for (int mt = 0; mt < 4; ++mt)                                \
            _Pragma("unroll") for (int nt = 0; nt < 4; ++nt)                            \
                acc[mt][nt] = MFMA16(af[mt], bfr[nt], acc[mt][nt]);                     \
    }

// ---------------- fused QKV GEMM: z selects (A, W, bias, out) -----------------
// XCD swizzle: raw -> (row=raw%64, col=raw/64) so dispatch%8 = row%8: all 8
// col-blocks of one A row-panel share an XCD L2.
// Epilogue: acc -> LDS (fp32, stride 132) -> row-major re-read -> bias+rope
// pairwise in-lane -> 32B/thread bf16 stores (128B-contiguous per head row).
// NOTE: Q (z==0) is pre-scaled by 0.125*log2(e) so attn computes exp2(S) directly.
__global__ __launch_bounds__(256) void gemm_qkv(const bf16_t* __restrict__ Cb,
                                                const bf16_t* __restrict__ Wt3,
                                                const float* __restrict__ bq,
                                                const float* __restrict__ bk,
                                                const float* __restrict__ bv,
                                                bf16_t* __restrict__ Qr,
                                                bf16_t* __restrict__ Kr,
                                                bf16_t* __restrict__ Vr,
                                                const float* __restrict__ cosT,
                                                const float* __restrict__ sinT) {
    __shared__ __align__(16) unsigned char smem[32 * 132 * 4];  // 16.9 KB
    bf16_t* As = (bf16_t*)smem;
    bf16_t* Bs = (bf16_t*)(smem + 8192);
    float* eps = (float*)smem;
    const int z = blockIdx.z;
    const bf16_t* A = Cb + (size_t)z * BATCH * SEQ * DIMC;
    const bf16_t* Bt = Wt3 + (size_t)z * DIMC * DIMC;
    const float* bias = (z == 0) ? bq : ((z == 1) ? bk : bv);
    bf16_t* outp = (z == 0) ? Qr : ((z == 1) ? Kr : Vr);
    const bool rope = (z < 2);
    const int tid = threadIdx.x;
    const int w = tid >> 6;
    const int lane = tid & 63;
    const int l15 = lane & 15;
    const int quad = lane >> 4;
    const int wr = w >> 1, wc = w & 1;
    const int raw = blockIdx.y * 8 + blockIdx.x;
    const int row0 = (raw & 63) * 128, col0 = (raw >> 6) * 128;
    GEMM_KLOOP(A, Bt)
    // bias per owned col (added before LDS, rope applied after re-read)
    float bvl[4];
    #pragma unroll
    for (int nt = 0; nt < 4; ++nt) bvl[nt] = bias[col0 + wc * 64 + nt * 16 + l15];
    // read-phase thread mapping
    const int lr = tid >> 3;  // 0..31 local row
    const int cg = tid & 7;   // 0..7 col group of 16
    const int c0 = cg * 16;
    const int h = (col0 + c0) >> 6;
    const int dbase = (col0 + c0) & 63;
    #pragma unroll
    for (int p = 0; p < 4; ++p) {  // p = mt slab (32 rows: wr0 & wr1)
        __syncthreads();
        #pragma unroll
        for (int nt = 0; nt < 4; ++nt)
            #pragma unroll
            for (int r = 0; r < 4; ++r)
                eps[(wr * 16 + quad * 4 + r) * 132 + wc * 64 + nt * 16 + l15] =
                    acc[p][nt][r] + bvl[nt];
        __syncthreads();
        const int grow = row0 + (lr >> 4) * 64 + p * 16 + (lr & 15);
        const int t = grow & (SEQ - 1);
        const int bb = grow >> 11;
        float vals[16];
        #pragma unroll
        for (int q4 = 0; q4 < 4; ++q4) {
            f32x4 vv = *(const f32x4*)&eps[lr * 132 + c0 + q4 * 4];
            vals[q4 * 4 + 0] = vv[0]; vals[q4 * 4 + 1] = vv[1];
            vals[q4 * 4 + 2] = vv[2]; vals[q4 * 4 + 3] = vv[3];
        }
        bf16x8 o0, o1;
        if (rope) {
            // fold softmax scale*log2(e) into Q only
            const float osc = (z == 0) ? 0.18033688011112043f : 1.0f;
            const int pbase = t * 32 + (dbase >> 1);
            const float4 cs0 = *(const float4*)&cosT[pbase];
            const float4 cs1 = *(const float4*)&cosT[pbase + 4];
            const float4 sn0 = *(const float4*)&sinT[pbase];
            const float4 sn1 = *(const float4*)&sinT[pbase + 4];
            const float cc[8] = {cs0.x, cs0.y, cs0.z, cs0.w, cs1.x, cs1.y, cs1.z, cs1.w};
            const float ss[8] = {sn0.x, sn0.y, sn0.z, sn0.w, sn1.x, sn1.y, sn1.z, sn1.w};
            #pragma unroll
            for (int i = 0; i < 8; ++i) {
                const float e = vals[2 * i], o = vals[2 * i + 1];
                const float oe = (e * cc[i] - o * ss[i]) * osc;
                const float oo = (e * ss[i] + o * cc[i]) * osc;
                if (i < 4) { o0[2 * i] = (bf16_t)oe; o0[2 * i + 1] = (bf16_t)oo; }
                else { o1[2 * (i - 4)] = (bf16_t)oe; o1[2 * (i - 4) + 1] = (bf16_t)oo; }
            }
        } else {
            #pragma unroll
            for (int i = 0; i < 8; ++i) o0[i] = (bf16_t)vals[i];
            #pragma unroll
            for (int i = 0; i < 8; ++i) o1[i] = (bf16_t)vals[8 + i];
        }
        bf16_t* dst = outp + (((size_t)bb * NH + h) * SEQ + t) * HD + dbase;
        *(bf16x8*)dst = o0;
        *(bf16x8*)(dst + 8) = o1;
    }
}

// ---------------- output GEMM (fp32 out, XCD-swizzled) -----------------
__global__ __launch_bounds__(256) void gemm_o(const bf16_t* __restrict__ A,
                                              const bf16_t* __restrict__ Bt,
                                              const float* __restrict__ bias,
                                              float* __restrict__ out) {
    __shared__ __align__(16) unsigned char smem[16384];
    bf16_t* As = (bf16_t*)smem;
    bf16_t* Bs = (bf16_t*)(smem + 8192);
    const int tid = threadIdx.x;
    const int w = tid >> 6;
    const int lane = tid & 63;
    const int l15 = lane & 15;
    const int quad = lane >> 4;
    const int wr = w >> 1, wc = w & 1;
    const int raw = blockIdx.y * 8 + blockIdx.x;
    const int row0 = (raw & 63) * 128, col0 = (raw >> 6) * 128;
    GEMM_KLOOP(A, Bt)
    #pragma unroll
    for (int nt = 0; nt < 4; ++nt) {
        const int col = col0 + wc * 64 + nt * 16 + l15;
        const float bvl = bias[col];
        #pragma unroll
        for (int mt = 0; mt < 4; ++mt) {
            #pragma unroll
            for (int r = 0; r < 4; ++r) {
                const int row = row0 + wr * 64 + mt * 16 + quad * 4 + r;
                out[(size_t)row * DIMC + col] = acc[mt][nt][r] + bvl;
            }
        }
    }
}

// ---------------- flash attention (causal, no-max softmax, S^T trick) -----------------
// Qr/Kr/Vr: bf16 [B,H,S,64] (rope on Q,K; Q pre-scaled by 0.125*log2e). O: bf16 [B*S,1024]
// v2: single-barrier software pipeline. Ks/Vt double-buffered; iteration it
// prefetches K(it+1) via global_load_lds and V(it+1) into regs at the TOP,
// computes QK/exp/PV on buffer cur, transposes V(it+1)->Vt[nxt] at the BOTTOM,
// then one __syncthreads() (its vmcnt/lgkm drain fences both buffers for it+1).
// Grid: (bh, 16) with j = 15 - blockIdx.y => longest blocks (32 iters) dispatch
// first (LPT); dispatch%8 = bh%8 keeps each head's K/V on one XCD L2.
__global__ __launch_bounds__(256) void attn_kernel(const bf16_t* __restrict__ Qr,
                                                   const bf16_t* __restrict__ Kr,
                                                   const bf16_t* __restrict__ Vr,
                                                   bf16_t* __restrict__ O) {
    __shared__ bf16_t Ks[2][64 * 64];   // swizzled [s][d], double-buffered (16 KB)
    __shared__ bf16_t Vt[2][64 * 72];   // [d][s] stride 72, double-buffered (18 KB)
    __shared__ bf16_t Ps[4][32 * 72];   // per-wave [t-local][s], stride 72 (18 KB)
    const int tid = threadIdx.x;
    const int w = tid >> 6;
    const int lane = tid & 63;
    const int l15 = lane & 15;
    const int quad = lane >> 4;
    const int bh = blockIdx.x;
    const int b = bh >> 4, h = bh & 15;
    const bf16_t* Qb = Qr + (size_t)bh * SEQ * HD;
    const bf16_t* Kb = Kr + (size_t)bh * SEQ * HD;
    const bf16_t* Vb = Vr + (size_t)bh * SEQ * HD;

    bf16x8 ones;
    #pragma unroll
    for (int j8 = 0; j8 < 8; ++j8) ones[j8] = (bf16_t)1.0f;
    // identity B-fragments for in-register V transpose: B[k][n] = (k == ch*16 + n)
    bf16x8 idB[2];
    #pragma unroll
    for (int ch = 0; ch < 2; ++ch)
        #pragma unroll
        for (int j8 = 0; j8 < 8; ++j8)
            idB[ch][j8] = (quad * 8 + j8 == ch * 16 + l15) ? (bf16_t)1.0f : (bf16_t)0.0f;

    // K async staging lane constants (chunk = 8 s-rows x 64 d)
    const int sIn = lane >> 3;              // s within chunk
    const int gK = ((lane & 7) ^ sIn) * 8;  // swizzled source d-offset
    const int fK = (l15 & 7);               // read-side swizzle key

// transpose 16 V rows (this wave's) into Vt[buf] via identity MFMA
#define VTRANS(buf, a0, a1)                                                      \
    {                                                                            \
        _Pragma("unroll") for (int c = 0; c < 4; ++c) {                          \
            f32x4 zt = {};                                                       \
            f32x4 tv = MFMA16((c < 2) ? (a0) : (a1), idB[c & 1], zt);            \
            bf16x4 pkt;                                                          \
            _Pragma("unroll") for (int rr = 0; rr < 4; ++rr)                     \
                pkt[rr] = (bf16_t)tv[rr];                                        \
            *(bf16x4*)&Vt[buf][(c * 16 + l15) * 72 + w * 16 + quad * 4] = pkt;   \
        }                                                                        \
    }

    const int j = 15 - (int)blockIdx.y;  // big tiles first (LPT)
    const int q0 = j * 128;
    // Q fragments (B-operand): Q[t = q0+mg*64+w*16+l15][d = kc*32+quad*8..]
    bf16x8 qa[2][2];
    #pragma unroll
    for (int mg = 0; mg < 2; ++mg)
        #pragma unroll
        for (int kc = 0; kc < 2; ++kc)
            qa[mg][kc] = *(const bf16x8*)(Qb + (size_t)(q0 + mg * 64 + w * 16 + l15) * HD +
                                          kc * 32 + quad * 8);
    f32x4 acco[2][4] = {};
    f32x4 accl[2] = {};
    const int nIter = 2 * j + 2;

    // prologue: stage tile 0 (K async, V via reg+transpose), one barrier
    #pragma unroll
    for (int ci = 0; ci < 2; ++ci) {
        const int c = 2 * w + ci;
        async_copy16(&Ks[0][c * 512], Kb + (size_t)(c * 8 + sIn) * HD + gK);
    }
    {
        const bf16_t* vsrc = Vb + (size_t)(w * 16 + l15) * HD + quad * 8;
        bf16x8 pv0 = *(const bf16x8*)vsrc;
        bf16x8 pv1 = *(const bf16x8*)(vsrc + 32);
        VTRANS(0, pv0, pv1);
    }
    __syncthreads();

    int cur = 0;
    for (int it = 0; it < nIter; ++it) {
        const int nxt = cur ^ 1;
        const bool hn = (it + 1 < nIter);
        bf16x8 av0, av1;
        if (hn) {  // prefetch tile it+1: K -> Ks[nxt] (async), V -> regs
            const int s1 = (it + 1) * 64;
            #pragma unroll
            for (int ci = 0; ci < 2; ++ci) {
                const int c = 2 * w + ci;
                async_copy16(&Ks[nxt][c * 512], Kb + (size_t)(s1 + c * 8 + sIn) * HD + gK);
            }
            const bf16_t* vsrc = Vb + (size_t)(s1 + w * 16 + l15) * HD + quad * 8;
            av0 = *(const bf16x8*)vsrc;
            av1 = *(const bf16x8*)(vsrc + 32);
        }
        // K fragments (A-operand): K[s = mt*16+l15][d], swizzled address
        bf16x8 kb[4][2];
        #pragma unroll
        for (int mt = 0; mt < 4; ++mt)
            #pragma unroll
            for (int kc = 0; kc < 2; ++kc)
                kb[mt][kc] = *(const bf16x8*)&Ks[cur][(mt * 16 + l15) * 64 +
                                                      (((kc * 4 + quad) ^ fK) << 3)];
        const bool skip0 = (it == 2 * j + 1);  // mg=0 fully masked on last iter
        // S^T = K Q^T (Q pre-scaled, so P = exp2(S^T) directly)
        f32x4 zz[2][4];
        __builtin_amdgcn_s_setprio(1);
        #pragma unroll
        for (int mg = 0; mg < 2; ++mg) {
            if (mg == 0 && skip0) continue;
            #pragma unroll
            for (int mt = 0; mt < 4; ++mt) {
                f32x4 z = {};
                z = MFMA16(kb[mt][0], qa[mg][0], z);
                z = MFMA16(kb[mt][1], qa[mg][1], z);
                zz[mg][mt] = z;
            }
        }
        __builtin_amdgcn_s_setprio(0);
        #pragma unroll
        for (int mg = 0; mg < 2; ++mg) {
            if (mg == 0 && skip0) continue;
            const bool diag = (it == 2 * j + mg);
            #pragma unroll
            for (int mt = 0; mt < 4; ++mt) {
                bf16x4 pk;
                #pragma unroll
                for (int r = 0; r < 4; ++r) {
                    float v = zz[mg][mt][r];
                    if (diag && (mt * 16 + quad * 4 + r > w * 16 + l15)) v = -INFINITY;
                    pk[r] = (bf16_t)fast_exp2(v);
                }
                *(bf16x4*)&Ps[w][(mg * 16 + l15) * 72 + mt * 16 + quad * 4] = pk;
            }
        }
        asm volatile("s_waitcnt lgkmcnt(0)" ::: "memory");
        // V^T fragments (B-operand) from Vt[cur]
        bf16x8 vb[4][2];
        #pragma unroll
        for (int dt = 0; dt < 4; ++dt)
            #pragma unroll
            for (int kc = 0; kc < 2; ++kc)
                vb[dt][kc] = *(const bf16x8*)&Vt[cur][(dt * 16 + l15) * 72 + kc * 32 + quad * 8];
        #pragma unroll
        for (int mg = 0; mg < 2; ++mg) {
            if (mg == 0 && skip0) continue;
            const bf16x8 pa0 = *(const bf16x8*)&Ps[w][(mg * 16 + l15) * 72 + quad * 8];
            const bf16x8 pa1 = *(const bf16x8*)&Ps[w][(mg * 16 + l15) * 72 + 32 + quad * 8];
            __builtin_amdgcn_s_setprio(1);
            #pragma unroll
            for (int dt = 0; dt < 4; ++dt) {
                acco[mg][dt] = MFMA16(pa0, vb[dt][0], acco[mg][dt]);
                acco[mg][dt] = MFMA16(pa1, vb[dt][1], acco[mg][dt]);
            }
            accl[mg] = MFMA16(pa0, ones, accl[mg]);
            accl[mg] = MFMA16(pa1, ones, accl[mg]);
            __builtin_amdgcn_s_setprio(0);
        }
        // transpose prefetched V(it+1) into Vt[nxt] (vmcnt wait lands here,
        // hidden behind the QK/exp/PV phase above)
        if (hn) VTRANS(nxt, av0, av1);
        __syncthreads();  // drains vmcnt (Ks[nxt] DMA) + lgkm (Vt[nxt] writes)
        cur = nxt;
    }
    // epilogue: O[t][d], t = q0+mg*64+w*16+quad*4+r, d = dt*16+l15
    #pragma unroll
    for (int mg = 0; mg < 2; ++mg) {
        #pragma unroll
        for (int r = 0; r < 4; ++r) {
            const float inv = 1.0f / accl[mg][r];
            const int trow = q0 + mg * 64 + w * 16 + quad * 4 + r;
            bf16_t* orow = O + ((size_t)(b * SEQ + trow)) * DIMC + h * HD;
            #pragma unroll
            for (int dt = 0; dt < 4; ++dt)
                orow[dt * 16 + l15] = (bf16_t)(acco[mg][dt][r] * inv);
        }
    }
#undef VTRANS
}

extern "C" void kernel_launch(void* const* d_in, const int* in_sizes, int n_in,
                              void* d_out, int out_size, void* d_ws, size_t ws_size,
                              hipStream_t stream) {
    const float* query = (const float*)d_in[0];
    const float* key = (const float*)d_in[1];
    const float* value = (const float*)d_in[2];
    const float* Wq = (const float*)d_in[3];
    const float* bq = (const float*)d_in[4];
    const float* Wk = (const float*)d_in[5];
    const float* bk = (const float*)d_in[6];
    const float* Wv = (const float*)d_in[7];
    const float* bv = (const float*)d_in[8];
    const float* Wo = (const float*)d_in[9];
    const float* bo = (const float*)d_in[10];

    char* ws = (char*)d_ws;
    const size_t WT_BYTES = (size_t)DIMC * DIMC * sizeof(bf16_t);          // 2 MB
    const size_t ACT_BYTES = (size_t)BATCH * SEQ * DIMC * sizeof(bf16_t);  // 16 MB
    bf16_t* WT = (bf16_t*)ws;  // WqT,WkT,WvT,WoT consecutive (8 MB)
    bf16_t* WoT = WT + 3 * (size_t)DIMC * DIMC;
    float* cosT = (float*)(ws + 4 * WT_BYTES);
    float* sinT = (float*)(ws + 4 * WT_BYTES + 262144);
    bf16_t* Cb = (bf16_t*)(ws + 4 * WT_BYTES + 2 * 262144);  // 3x16 MB bf16 inputs
    bf16_t* Qr = (bf16_t*)((char*)Cb + 3 * ACT_BYTES);
    bf16_t* Kr = (bf16_t*)((char*)Cb + 4 * ACT_BYTES);
    bf16_t* Vr = (bf16_t*)((char*)Cb + 5 * ACT_BYTES);
    bf16_t* Ob = Cb;  // attention output aliases Cq (free after QKV GEMMs)

    transpose_cvt<<<dim3(32, 32, 4), 256, 0, stream>>>(Wq, Wk, Wv, Wo, WT);
    rope_tab<<<dim3(256), 256, 0, stream>>>(cosT, sinT);
    cvt3<<<dim3(4096, 3), 256, 0, stream>>>(query, key, value, Cb);
    gemm_qkv<<<dim3(DIMC / 128, (BATCH * SEQ) / 128, 3), 256, 0, stream>>>(
        Cb, WT, bq, bk, bv, Qr, Kr, Vr, cosT, sinT);
    attn_kernel<<<dim3(BATCH * NH, 16), 256, 0, stream>>>(Qr, Kr, Vr, Ob);
    gemm_o<<<dim3(DIMC / 128, (BATCH * SEQ) / 128), 256, 0, stream>>>(Ob, WoT, bo, (float*)d_out);
}

// Round 2
// 332.457 us; speedup vs baseline: 1.0240x; 1.0073x over previous
//
#include <hip/hip_runtime.h>
#include <cstdint>
#include <math.h>

typedef __bf16 bf16_t;
typedef __bf16 bf16x8 __attribute__((ext_vector_type(8)));
typedef __bf16 bf16x4 __attribute__((ext_vector_type(4)));
typedef float f32x4 __attribute__((ext_vector_type(4)));

#define MFMA16(a, b, c) __builtin_amdgcn_mfma_f32_16x16x32_bf16((a), (b), (c), 0, 0, 0)

static constexpr int BATCH = 4;
static constexpr int SEQ = 2048;
static constexpr int DIMC = 1024;
static constexpr int NH = 16;
static constexpr int HD = 64;

__device__ __forceinline__ void async_copy16(void* lds, const void* g) {
    __builtin_amdgcn_global_load_lds(
        (const __attribute__((address_space(1))) void*)g,
        (__attribute__((address_space(3))) void*)lds, 16, 0, 0);
}

__device__ __forceinline__ float fast_exp2(float x) {
#if __has_builtin(__builtin_amdgcn_exp2f)
    return __builtin_amdgcn_exp2f(x);
#else
    return __expf(x * 0.6931471805599453f);
#endif
}

// ---------------- fp32 -> bf16 elementwise convert, 3 tensors -----------------
__global__ __launch_bounds__(256) void cvt3(const float* __restrict__ q,
                                            const float* __restrict__ k,
                                            const float* __restrict__ v,
                                            bf16_t* __restrict__ out) {
    const float* in = (blockIdx.y == 0) ? q : ((blockIdx.y == 1) ? k : v);
    bf16_t* o = out + (size_t)blockIdx.y * BATCH * SEQ * DIMC;
    const int i = blockIdx.x * 256 + threadIdx.x;  // 8 elems per thread
    const float4 f0 = ((const float4*)in)[i * 2];
    const float4 f1 = ((const float4*)in)[i * 2 + 1];
    bf16x8 vv;
    vv[0] = (bf16_t)f0.x; vv[1] = (bf16_t)f0.y; vv[2] = (bf16_t)f0.z; vv[3] = (bf16_t)f0.w;
    vv[4] = (bf16_t)f1.x; vv[5] = (bf16_t)f1.y; vv[6] = (bf16_t)f1.z; vv[7] = (bf16_t)f1.w;
    ((bf16x8*)o)[i] = vv;
}

// ---------------- weight transpose + fp32->bf16 convert -----------------
__global__ __launch_bounds__(256) void transpose_cvt(const float* __restrict__ W0,
                                                     const float* __restrict__ W1,
                                                     const float* __restrict__ W2,
                                                     const float* __restrict__ W3,
                                                     bf16_t* __restrict__ out) {
    const float* Ws[4] = {W0, W1, W2, W3};
    const float* W = Ws[blockIdx.z];
    bf16_t* Wt = out + (size_t)blockIdx.z * DIMC * DIMC;
    __shared__ float tile[32][33];
    const int tx = threadIdx.x & 31;
    const int ty = threadIdx.x >> 5;
    const int x0 = blockIdx.x * 32;
    const int y0 = blockIdx.y * 32;
    #pragma unroll
    for (int j = ty; j < 32; j += 8)
        tile[j][tx] = W[(size_t)(y0 + j) * DIMC + x0 + tx];
    __syncthreads();
    #pragma unroll
    for (int j = ty; j < 32; j += 8)
        Wt[(size_t)(x0 + j) * DIMC + y0 + tx] = (bf16_t)tile[tx][j];
}

// ---------------- rope tables -----------------
__global__ __launch_bounds__(256) void rope_tab(float* __restrict__ cosT, float* __restrict__ sinT) {
    const int idx = blockIdx.x * 256 + threadIdx.x;  // 65536 = 2048*32
    const int t = idx >> 5;
    const int p = idx & 31;
    const float inv = exp2f(-0.41524101186092029f * (float)p);
    const float ang = (float)t * inv;
    float s, c;
    sincosf(ang, &s, &c);
    cosT[idx] = c;
    sinT[idx] = s;
}

// ===== 256-col GEMM core: BN=256, BK=32, 8 waves (2x4), triple-buffered LDS,
// 2-tiles-ahead global_load_lds staging, counted vmcnt, 1 raw s_barrier/K-tile.
// MI = m-frags per wave (8 -> BM=256, 4 -> BM=128). Per-wave output MI*16 x 64.
// LDS swizzle: element (row r, 16B-granule g) at r*64B + ((g ^ f(r&15))*16B),
// f(r)=(r&3)^((r>>2)&3) — same proven scheme as the 128^2 kernel.
// Safety argument for the pipeline (buffers mod 3, stage t+2 at iter t):
//  - reads of buf[(t+2)%3]=buf[(t-1)%3] are lgkm-drained before each wave's
//    iter-(t-1) MFMAs, hence before the iter-t barrier, hence before any DMA.
//  - tile-t DMA completion: own loads via vmcnt(4) (only tile t+1's 4 newer),
//    other waves' via the barrier after their own vmcnt wait.
template <int MI>
__device__ __forceinline__ void gemm_core(const bf16_t* __restrict__ A,
                                          const bf16_t* __restrict__ Bt,
                                          const int row0, const int col0,
                                          bf16_t* As, bf16_t* Bs, const int tid,
                                          f32x4 (&acc)[MI][4]) {
    constexpr int ABUF = MI * 32 * 32;  // elems per A buffer (8192 / 4096)
    constexpr int BBUF = 256 * 32;      // 8192
    constexpr int NT = DIMC / 32;       // 32 K-tiles
    const int wid = tid >> 6;
    const int lane = tid & 63;
    const int l15 = lane & 15;
    const int quad = lane >> 4;
    const int wr = wid >> 2;  // 0..1
    const int wc = wid & 3;   // 0..3
    const int rIn = lane >> 2;
    const int gW = ((lane & 3) ^ ((rIn & 3) ^ ((rIn >> 2) & 3))) * 8;
    const int fR = (l15 & 3) ^ ((l15 >> 2) & 3);

#define STAGE_TILE(bi, kt)                                                              \
    {                                                                                   \
        const int k0_ = (kt)*32;                                                        \
        bf16_t* as_ = As + (bi)*ABUF;                                                   \
        bf16_t* bs_ = Bs + (bi)*BBUF;                                                   \
        if constexpr (MI == 8) {                                                        \
            _Pragma("unroll") for (int ci = 0; ci < 2; ++ci) {                          \
                const int c = 2 * wid + ci;                                             \
                async_copy16(&as_[c * 512],                                             \
                             A + (size_t)(row0 + c * 16 + rIn) * DIMC + k0_ + gW);      \
            }                                                                           \
        } else {                                                                        \
            async_copy16(&as_[wid * 512],                                               \
                         A + (size_t)(row0 + wid * 16 + rIn) * DIMC + k0_ + gW);        \
        }                                                                               \
        _Pragma("unroll") for (int ci = 0; ci < 2; ++ci) {                              \
            const int c = 2 * wid + ci;                                                 \
            async_copy16(&bs_[c * 512],                                                 \
                         Bt + (size_t)(col0 + c * 16 + rIn) * DIMC + k0_ + gW);         \
        }                                                                               \
    }

    STAGE_TILE(0, 0)
    STAGE_TILE(1, 1)
    int rb = 0;
    for (int t = 0; t < NT; ++t) {
        if (t == NT - 1) {
            asm volatile("s_waitcnt vmcnt(0)" ::: "memory");
        } else {
            if constexpr (MI == 8)
                asm volatile("s_waitcnt vmcnt(4)" ::: "memory");
            else
                asm volatile("s_waitcnt vmcnt(3)" ::: "memory");
        }
        asm volatile("s_barrier" ::: "memory");
        if (t + 2 < NT) {
            int sb = rb + 2;
            if (sb >= 3) sb -= 3;
            STAGE_TILE(sb, t + 2)
        }
        const bf16_t* as = As + rb * ABUF;
        const bf16_t* bs = Bs + rb * BBUF;
        bf16x8 bfrag[4];
        #pragma unroll
        for (int ni = 0; ni < 4; ++ni)
            bfrag[ni] = *(const bf16x8*)&bs[(wc * 64 + ni * 16 + l15) * 32 + ((quad ^ fR) << 3)];
        bf16x8 afrag[MI];
        #pragma unroll
        for (int mi = 0; mi < MI; ++mi)
            afrag[mi] =
                *(const bf16x8*)&as[(wr * (MI * 16) + mi * 16 + l15) * 32 + ((quad ^ fR) << 3)];
        __builtin_amdgcn_s_setprio(1);
        #pragma unroll
        for (int mi = 0; mi < MI; ++mi)
            #pragma unroll
            for (int ni = 0; ni < 4; ++ni)
                acc[mi][ni] = MFMA16(afrag[mi], bfrag[ni], acc[mi][ni]);
        __builtin_amdgcn_s_setprio(0);
        rb = rb + 1 == 3 ? 0 : rb + 1;
    }
#undef STAGE_TILE
}

// ---------------- fused QKV GEMM (256x256 tile, 512 thr) -----------------
// z selects (A, W, bias, out). Q (z==0) pre-scaled by 0.125*log2(e).
// Epilogue: per mi-slab (32 rows x 256 cols) acc -> LDS fp32 (stride 264) ->
// row-major re-read -> bias already added -> rope pairwise -> 32B bf16 stores.
__global__ __launch_bounds__(512, 2) void gemm_qkv(const bf16_t* __restrict__ Cb,
                                                   const bf16_t* __restrict__ Wt3,
                                                   const float* __restrict__ bq,
                                                   const float* __restrict__ bk,
                                                   const float* __restrict__ bv,
                                                   bf16_t* __restrict__ Qr,
                                                   bf16_t* __restrict__ Kr,
                                                   bf16_t* __restrict__ Vr,
                                                   const float* __restrict__ cosT,
                                                   const float* __restrict__ sinT) {
    __shared__ __align__(16) unsigned char smem[98304];  // 3x16KB A + 3x16KB B
    bf16_t* As = (bf16_t*)smem;
    bf16_t* Bs = (bf16_t*)(smem + 49152);
    float* eps = (float*)smem;  // epilogue alias: 32 x 264 fp32 = 33.8KB
    const int z = blockIdx.z;
    const bf16_t* A = Cb + (size_t)z * BATCH * SEQ * DIMC;
    const bf16_t* Bt = Wt3 + (size_t)z * DIMC * DIMC;
    const float* bias = (z == 0) ? bq : ((z == 1) ? bk : bv);
    bf16_t* outp = (z == 0) ? Qr : ((z == 1) ? Kr : Vr);
    const bool rope = (z < 2);
    const int tid = threadIdx.x;
    const int row0 = blockIdx.y * 256, col0 = blockIdx.x * 256;
    f32x4 acc[8][4] = {};
    gemm_core<8>(A, Bt, row0, col0, As, Bs, tid, acc);

    const int wid = tid >> 6;
    const int lane = tid & 63;
    const int l15 = lane & 15;
    const int quad = lane >> 4;
    const int wr = wid >> 2, wc = wid & 3;
    float bvl[4];
    #pragma unroll
    for (int ni = 0; ni < 4; ++ni) bvl[ni] = bias[col0 + wc * 64 + ni * 16 + l15];
    // read-phase mapping: 512 threads = 32 rows x 16 col-groups of 16
    const int lr = tid >> 4;
    const int cg = tid & 15;
    const int c0 = cg * 16;
    const int h = (col0 + c0) >> 6;
    const int dbase = c0 & 63;
    const float osc = (z == 0) ? 0.18033688011112043f : 1.0f;
    #pragma unroll
    for (int p = 0; p < 8; ++p) {  // p = mi slab: rows {wr*128 + p*16 + 0..15}
        __syncthreads();
        #pragma unroll
        for (int ni = 0; ni < 4; ++ni)
            #pragma unroll
            for (int r = 0; r < 4; ++r)
                eps[(wr * 16 + quad * 4 + r) * 264 + wc * 64 + ni * 16 + l15] =
                    acc[p][ni][r] + bvl[ni];
        __syncthreads();
        const int grow = row0 + (lr >> 4) * 128 + p * 16 + (lr & 15);
        const int tq = grow & (SEQ - 1);
        const int bb = grow >> 11;
        float vals[16];
        #pragma unroll
        for (int q4 = 0; q4 < 4; ++q4) {
            f32x4 vv = *(const f32x4*)&eps[lr * 264 + c0 + q4 * 4];
            vals[q4 * 4 + 0] = vv[0]; vals[q4 * 4 + 1] = vv[1];
            vals[q4 * 4 + 2] = vv[2]; vals[q4 * 4 + 3] = vv[3];
        }
        bf16x8 o0, o1;
        if (rope) {
            const int pbase = tq * 32 + (dbase >> 1);
            const float4 cs0 = *(const float4*)&cosT[pbase];
            const float4 cs1 = *(const float4*)&cosT[pbase + 4];
            const float4 sn0 = *(const float4*)&sinT[pbase];
            const float4 sn1 = *(const float4*)&sinT[pbase + 4];
            const float cc[8] = {cs0.x, cs0.y, cs0.z, cs0.w, cs1.x, cs1.y, cs1.z, cs1.w};
            const float ss[8] = {sn0.x, sn0.y, sn0.z, sn0.w, sn1.x, sn1.y, sn1.z, sn1.w};
            #pragma unroll
            for (int i = 0; i < 8; ++i) {
                const float e = vals[2 * i], o = vals[2 * i + 1];
                const float oe = (e * cc[i] - o * ss[i]) * osc;
                const float oo = (e * ss[i] + o * cc[i]) * osc;
                if (i < 4) { o0[2 * i] = (bf16_t)oe; o0[2 * i + 1] = (bf16_t)oo; }
                else { o1[2 * (i - 4)] = (bf16_t)oe; o1[2 * (i - 4) + 1] = (bf16_t)oo; }
            }
        } else {
            #pragma unroll
            for (int i = 0; i < 8; ++i) o0[i] = (bf16_t)vals[i];
            #pragma unroll
            for (int i = 0; i < 8; ++i) o1[i] = (bf16_t)vals[8 + i];
        }
        bf16_t* dst = outp + (((size_t)bb * NH + h) * SEQ + tq) * HD + dbase;
        *(bf16x8*)dst = o0;
        *(bf16x8*)(dst + 8) = o1;
    }
}

// ---------------- output GEMM (128x256 tile, fp32 out) -----------------
__global__ __launch_bounds__(512, 2) void gemm_o(const bf16_t* __restrict__ A,
                                                 const bf16_t* __restrict__ Bt,
                                                 const float* __restrict__ bias,
                                                 float* __restrict__ out) {
    __shared__ __align__(16) unsigned char smem[73728];  // 3x8KB A + 3x16KB B
    bf16_t* As = (bf16_t*)smem;
    bf16_t* Bs = (bf16_t*)(smem + 24576);
    const int tid = threadIdx.x;
    const int row0 = blockIdx.y * 128, col0 = blockIdx.x * 256;
    f32x4 acc[4][4] = {};
    gemm_core<4>(A, Bt, row0, col0, As, Bs, tid, acc);
    const int wid = tid >> 6;
    const int lane = tid & 63;
    const int l15 = lane & 15;
    const int quad = lane >> 4;
    const int wr = wid >> 2, wc = wid & 3;
    #pragma unroll
    for (int ni = 0; ni < 4; ++ni) {
        const int col = col0 + wc * 64 + ni * 16 + l15;
        const float bvl = bias[col];
        #pragma unroll
        for (int mi = 0; mi < 4; ++mi) {
            #pragma unroll
            for (int r = 0; r < 4; ++r) {
                const int row = row0 + wr * 64 + mi * 16 + quad * 4 + r;
                out[(size_t)row * DIMC + col] = acc[mi][ni][r] + bvl;
            }
        }
    }
}

// ---------------- flash attention (causal, no-max softmax, S^T trick) -----------------
// Qr/Kr/Vr: bf16 [B,H,S,64] (rope on Q,K; Q pre-scaled by 0.125*log2e). O: bf16 [B*S,1024]
// Single-barrier software pipeline, Ks/Vt double-buffered (see round-1 notes).
__global__ __launch_bounds__(256) void attn_kernel(const bf16_t* __restrict__ Qr,
                                                   const bf16_t* __restrict__ Kr,
                                                   const bf16_t* __restrict__ Vr,
                                                   bf16_t* __restrict__ O) {
    __shared__ bf16_t Ks[2][64 * 64];   // swizzled [s][d], double-buffered (16 KB)
    __shared__ bf16_t Vt[2][64 * 72];   // [d][s] stride 72, double-buffered (18 KB)
    __shared__ bf16_t Ps[4][32 * 72];   // per-wave [t-local][s], stride 72 (18 KB)
    const int tid = threadIdx.x;
    const int w = tid >> 6;
    const int lane = tid & 63;
    const int l15 = lane & 15;
    const int quad = lane >> 4;
    const int bh = blockIdx.x;
    const int b = bh >> 4, h = bh & 15;
    const bf16_t* Qb = Qr + (size_t)bh * SEQ * HD;
    const bf16_t* Kb = Kr + (size_t)bh * SEQ * HD;
    const bf16_t* Vb = Vr + (size_t)bh * SEQ * HD;

    bf16x8 ones;
    #pragma unroll
    for (int j8 = 0; j8 < 8; ++j8) ones[j8] = (bf16_t)1.0f;
    bf16x8 idB[2];
    #pragma unroll
    for (int ch = 0; ch < 2; ++ch)
        #pragma unroll
        for (int j8 = 0; j8 < 8; ++j8)
            idB[ch][j8] = (quad * 8 + j8 == ch * 16 + l15) ? (bf16_t)1.0f : (bf16_t)0.0f;

    const int sIn = lane >> 3;              // s within chunk
    const int gK = ((lane & 7) ^ sIn) * 8;  // swizzled source d-offset
    const int fK = (l15 & 7);               // read-side swizzle key

#define VTRANS(buf, a0, a1)                                                      \
    {                                                                            \
        _Pragma("unroll") for (int c = 0; c < 4; ++c) {                          \
            f32x4 zt = {};                                                       \
            f32x4 tv = MFMA16((c < 2) ? (a0) : (a1), idB[c & 1], zt);            \
            bf16x4 pkt;                                                          \
            _Pragma("unroll") for (int rr = 0; rr < 4; ++rr)                     \
                pkt[rr] = (bf16_t)tv[rr];                                        \
            *(bf16x4*)&Vt[buf][(c * 16 + l15) * 72 + w * 16 + quad * 4] = pkt;   \
        }                                                                        \
    }

    const int j = 15 - (int)blockIdx.y;  // big tiles first (LPT)
    const int q0 = j * 128;
    bf16x8 qa[2][2];
    #pragma unroll
    for (int mg = 0; mg < 2; ++mg)
        #pragma unroll
        for (int kc = 0; kc < 2; ++kc)
            qa[mg][kc] = *(const bf16x8*)(Qb + (size_t)(q0 + mg * 64 + w * 16 + l15) * HD +
                                          kc * 32 + quad * 8);
    f32x4 acco[2][4] = {};
    f32x4 accl[2] = {};
    const int nIter = 2 * j + 2;

    #pragma unroll
    for (int ci = 0; ci < 2; ++ci) {
        const int c = 2 * w + ci;
        async_copy16(&Ks[0][c * 512], Kb + (size_t)(c * 8 + sIn) * HD + gK);
    }
    {
        const bf16_t* vsrc = Vb + (size_t)(w * 16 + l15) * HD + quad * 8;
        bf16x8 pv0 = *(const bf16x8*)vsrc;
        bf16x8 pv1 = *(const bf16x8*)(vsrc + 32);
        VTRANS(0, pv0, pv1);
    }
    __syncthreads();

    int cur = 0;
    for (int it = 0; it < nIter; ++it) {
        const int nxt = cur ^ 1;
        const bool hn = (it + 1 < nIter);
        bf16x8 av0, av1;
        if (hn) {
            const int s1 = (it + 1) * 64;
            #pragma unroll
            for (int ci = 0; ci < 2; ++ci) {
                const int c = 2 * w + ci;
                async_copy16(&Ks[nxt][c * 512], Kb + (size_t)(s1 + c * 8 + sIn) * HD + gK);
            }
            const bf16_t* vsrc = Vb + (size_t)(s1 + w * 16 + l15) * HD + quad * 8;
            av0 = *(const bf16x8*)vsrc;
            av1 = *(const bf16x8*)(vsrc + 32);
        }
        bf16x8 kb[4][2];
        #pragma unroll
        for (int mt = 0; mt < 4; ++mt)
            #pragma unroll
            for (int kc = 0; kc < 2; ++kc)
                kb[mt][kc] = *(const bf16x8*)&Ks[cur][(mt * 16 + l15) * 64 +
                                                      (((kc * 4 + quad) ^ fK) << 3)];
        const bool skip0 = (it == 2 * j + 1);
        f32x4 zz[2][4];
        __builtin_amdgcn_s_setprio(1);
        #pragma unroll
        for (int mg = 0; mg < 2; ++mg) {
            if (mg == 0 && skip0) continue;
            #pragma unroll
            for (int mt = 0; mt < 4; ++mt) {
                f32x4 z = {};
                z = MFMA16(kb[mt][0], qa[mg][0], z);
                z = MFMA16(kb[mt][1], qa[mg][1], z);
                zz[mg][mt] = z;
            }
        }
        __builtin_amdgcn_s_setprio(0);
        #pragma unroll
        for (int mg = 0; mg < 2; ++mg) {
            if (mg == 0 && skip0) continue;
            const bool diag = (it == 2 * j + mg);
            #pragma unroll
            for (int mt = 0; mt < 4; ++mt) {
                bf16x4 pk;
                #pragma unroll
                for (int r = 0; r < 4; ++r) {
                    float v = zz[mg][mt][r];
                    if (diag && (mt * 16 + quad * 4 + r > w * 16 + l15)) v = -INFINITY;
                    pk[r] = (bf16_t)fast_exp2(v);
                }
                *(bf16x4*)&Ps[w][(mg * 16 + l15) * 72 + mt * 16 + quad * 4] = pk;
            }
        }
        asm volatile("s_waitcnt lgkmcnt(0)" ::: "memory");
        bf16x8 vb[4][2];
        #pragma unroll
        for (int dt = 0; dt < 4; ++dt)
            #pragma unroll
            for (int kc = 0; kc < 2; ++kc)
                vb[dt][kc] = *(const bf16x8*)&Vt[cur][(dt * 16 + l15) * 72 + kc * 32 + quad * 8];
        #pragma unroll
        for (int mg = 0; mg < 2; ++mg) {
            if (mg == 0 && skip0) continue;
            const bf16x8 pa0 = *(const bf16x8*)&Ps[w][(mg * 16 + l15) * 72 + quad * 8];
            const bf16x8 pa1 = *(const bf16x8*)&Ps[w][(mg * 16 + l15) * 72 + 32 + quad * 8];
            __builtin_amdgcn_s_setprio(1);
            #pragma unroll
            for (int dt = 0; dt < 4; ++dt) {
                acco[mg][dt] = MFMA16(pa0, vb[dt][0], acco[mg][dt]);
                acco[mg][dt] = MFMA16(pa1, vb[dt][1], acco[mg][dt]);
            }
            accl[mg] = MFMA16(pa0, ones, accl[mg]);
            accl[mg] = MFMA16(pa1, ones, accl[mg]);
            __builtin_amdgcn_s_setprio(0);
        }
        if (hn) VTRANS(nxt, av0, av1);
        __syncthreads();
        cur = nxt;
    }
    #pragma unroll
    for (int mg = 0; mg < 2; ++mg) {
        #pragma unroll
        for (int r = 0; r < 4; ++r) {
            const float inv = 1.0f / accl[mg][r];
            const int trow = q0 + mg * 64 + w * 16 + quad * 4 + r;
            bf16_t* orow = O + ((size_t)(b * SEQ + trow)) * DIMC + h * HD;
            #pragma unroll
            for (int dt = 0; dt < 4; ++dt)
                orow[dt * 16 + l15] = (bf16_t)(acco[mg][dt][r] * inv);
        }
    }
#undef VTRANS
}

extern "C" void kernel_launch(void* const* d_in, const int* in_sizes, int n_in,
                              void* d_out, int out_size, void* d_ws, size_t ws_size,
                              hipStream_t stream) {
    const float* query = (const float*)d_in[0];
    const float* key = (const float*)d_in[1];
    const float* value = (const float*)d_in[2];
    const float* Wq = (const float*)d_in[3];
    const float* bq = (const float*)d_in[4];
    const float* Wk = (const float*)d_in[5];
    const float* bk = (const float*)d_in[6];
    const float* Wv = (const float*)d_in[7];
    const float* bv = (const float*)d_in[8];
    const float* Wo = (const float*)d_in[9];
    const float* bo = (const float*)d_in[10];

    char* ws = (char*)d_ws;
    const size_t WT_BYTES = (size_t)DIMC * DIMC * sizeof(bf16_t);          // 2 MB
    const size_t ACT_BYTES = (size_t)BATCH * SEQ * DIMC * sizeof(bf16_t);  // 16 MB
    bf16_t* WT = (bf16_t*)ws;  // WqT,WkT,WvT,WoT consecutive (8 MB)
    bf16_t* WoT = WT + 3 * (size_t)DIMC * DIMC;
    float* cosT = (float*)(ws + 4 * WT_BYTES);
    float* sinT = (float*)(ws + 4 * WT_BYTES + 262144);
    bf16_t* Cb = (bf16_t*)(ws + 4 * WT_BYTES + 2 * 262144);  // 3x16 MB bf16 inputs
    bf16_t* Qr = (bf16_t*)((char*)Cb + 3 * ACT_BYTES);
    bf16_t* Kr = (bf16_t*)((char*)Cb + 4 * ACT_BYTES);
    bf16_t* Vr = (bf16_t*)((char*)Cb + 5 * ACT_BYTES);
    bf16_t* Ob = Cb;  // attention output aliases Cq (free after QKV GEMMs)

    transpose_cvt<<<dim3(32, 32, 4), 256, 0, stream>>>(Wq, Wk, Wv, Wo, WT);
    rope_tab<<<dim3(256), 256, 0, stream>>>(cosT, sinT);
    cvt3<<<dim3(4096, 3), 256, 0, stream>>>(query, key, value, Cb);
    gemm_qkv<<<dim3(DIMC / 256, (BATCH * SEQ) / 256, 3), 512, 0, stream>>>(
        Cb, WT, bq, bk, bv, Qr, Kr, Vr, cosT, sinT);
    attn_kernel<<<dim3(BATCH * NH, 16), 256, 0, stream>>>(Qr, Kr, Vr, Ob);
    gemm_o<<<dim3(DIMC / 256, (BATCH * SEQ) / 128), 512, 0, stream>>>(Ob, WoT, bo, (float*)d_out);
}